// Round 1
// baseline (785.281 us; speedup 1.0000x reference)
//
#include <hip/hip_runtime.h>
#include <hip/hip_bf16.h>
#include <math.h>

#define N_NODES 50000
#define N_EDGES 800000
#define DIM 128
#define CLS 32
#define NGRAPH 64
#define LN_EPS 1e-5f

static __device__ __forceinline__ int lower_bound_i(const int* a, int n, int key) {
    int lo = 0, hi = n;
    while (lo < hi) { int mid = (lo + hi) >> 1; if (a[mid] < key) lo = mid + 1; else hi = mid; }
    return lo;
}

// ---- CSR build -------------------------------------------------------------

__global__ void hist_kernel(const int* __restrict__ dst, int* __restrict__ cnt) {
    int e = blockIdx.x * blockDim.x + threadIdx.x;
    if (e < N_EDGES) atomicAdd(&cnt[dst[e]], 1);
}

__global__ __launch_bounds__(1024) void scan_kernel(const int* __restrict__ cnt,
                                                    int* __restrict__ off) {
    __shared__ int sd[1024];
    const int ITEMS = (N_NODES + 1023) / 1024;  // 49
    int i = threadIdx.x;
    int begin = i * ITEMS;
    int end = min(begin + ITEMS, N_NODES);
    int t = 0;
    for (int j = begin; j < end; j++) t += cnt[j];
    sd[i] = t;
    __syncthreads();
    for (int o = 1; o < 1024; o <<= 1) {
        int v = (i >= o) ? sd[i - o] : 0;
        __syncthreads();
        sd[i] += v;
        __syncthreads();
    }
    int base = sd[i] - t;  // exclusive prefix
    for (int j = begin; j < end; j++) { off[j] = base; base += cnt[j]; }
    if (i == 1023) off[N_NODES] = sd[1023];
}

__global__ void fill_csr_kernel(const int* __restrict__ src, const int* __restrict__ dst,
                                const int* __restrict__ off, int* __restrict__ cursor,
                                int* __restrict__ csr_src) {
    int e = blockIdx.x * blockDim.x + threadIdx.x;
    if (e < N_EDGES) {
        int d = dst[e];
        int pos = atomicAdd(&cursor[d], 1);
        csr_src[off[d] + pos] = src[e];
    }
}

// ---- Neighbor sum: S[n,:] = sum_{e in CSR[n]} X[src[e],:] ------------------
// One wave (64 lanes) per node, float2 per lane = 128 floats/row.

__global__ __launch_bounds__(256) void agg_kernel(const float* __restrict__ X,
                                                  const int* __restrict__ off,
                                                  const int* __restrict__ csr_src,
                                                  float* __restrict__ S) {
    int wave = threadIdx.x >> 6;
    int lane = threadIdx.x & 63;
    int n = blockIdx.x * 4 + wave;
    if (n >= N_NODES) return;
    int b = off[n], e = off[n + 1];
    float2 acc = make_float2(0.f, 0.f);
    for (int t = b; t < e; t++) {
        int s = csr_src[t];
        float2 v = ((const float2*)(X + (size_t)s * DIM))[lane];
        acc.x += v.x;
        acc.y += v.y;
    }
    ((float2*)(S + (size_t)n * DIM))[lane] = acc;
}

// ---- Fused layer: Xout = f(X@Wself + S@Wmsg + bself + deg*bmsg) ------------
// f = ReLU then optional LayerNorm. 64 rows x 128 cols per block.
// 256 threads: tx=0..15 -> 8 cols each, ty=0..15 -> 4 rows each.

__global__ __launch_bounds__(256) void layer_kernel(
    const float* __restrict__ X, const float* __restrict__ S,
    const float* __restrict__ Wself, const float* __restrict__ Wmsg,
    const float* __restrict__ bself, const float* __restrict__ bmsg,
    const int* __restrict__ off,
    const float* __restrict__ lng, const float* __restrict__ lnb,
    float* __restrict__ Xout, int do_ln) {
    __shared__ __align__(16) float at[128][68];  // [k][row], 34.8 KB, 68 keeps 16B align
    const int tx = threadIdx.x & 15;   // col group: cols tx*8 .. tx*8+7
    const int ty = threadIdx.x >> 4;   // row group: rows ty*4 .. ty*4+3
    const int row0 = blockIdx.x * 64;

    float acc[4][8];
#pragma unroll
    for (int r = 0; r < 4; r++)
#pragma unroll
        for (int c = 0; c < 8; c++) acc[r][c] = 0.f;

    for (int phase = 0; phase < 2; phase++) {
        const float* A = phase ? S : X;
        const float* W = phase ? Wmsg : Wself;
        __syncthreads();  // protect LDS reads of previous phase
#pragma unroll
        for (int i = 0; i < 8; i++) {
            int f = threadIdx.x + i * 256;  // float4 index 0..2047
            int row = f >> 5;               // 0..63
            int c4 = f & 31;
            int grow = row0 + row;
            float4 v = make_float4(0.f, 0.f, 0.f, 0.f);
            if (grow < N_NODES) v = *(const float4*)(A + (size_t)grow * DIM + c4 * 4);
            at[c4 * 4 + 0][row] = v.x;
            at[c4 * 4 + 1][row] = v.y;
            at[c4 * 4 + 2][row] = v.z;
            at[c4 * 4 + 3][row] = v.w;
        }
        __syncthreads();
        const float* wp = W + tx * 8;
#pragma unroll 4
        for (int k = 0; k < 128; k++) {
            float4 a4 = *(const float4*)&at[k][ty * 4];
            float4 w0 = *(const float4*)(wp + k * DIM);
            float4 w1 = *(const float4*)(wp + k * DIM + 4);
            float av[4] = {a4.x, a4.y, a4.z, a4.w};
            float wv[8] = {w0.x, w0.y, w0.z, w0.w, w1.x, w1.y, w1.z, w1.w};
#pragma unroll
            for (int r = 0; r < 4; r++)
#pragma unroll
                for (int c = 0; c < 8; c++) acc[r][c] += av[r] * wv[c];
        }
    }

    // epilogue: bias + deg*bmsg, relu, optional layernorm, store
#pragma unroll
    for (int r = 0; r < 4; r++) {
        int grow = row0 + ty * 4 + r;
        if (grow >= N_NODES) continue;  // uniform within each 16-lane tx-group
        float degf = (float)(off[grow + 1] - off[grow]);
        float v[8];
        float s1 = 0.f;
#pragma unroll
        for (int c = 0; c < 8; c++) {
            int col = tx * 8 + c;
            float h = acc[r][c] + bself[col] + degf * bmsg[col];
            h = fmaxf(h, 0.f);
            v[c] = h;
            s1 += h;
        }
        if (do_ln) {
#pragma unroll
            for (int m = 1; m < 16; m <<= 1) s1 += __shfl_xor(s1, m, 64);
            float mu = s1 * (1.0f / 128.0f);
            float s2 = 0.f;
#pragma unroll
            for (int c = 0; c < 8; c++) { float d = v[c] - mu; s2 += d * d; }
#pragma unroll
            for (int m = 1; m < 16; m <<= 1) s2 += __shfl_xor(s2, m, 64);
            float rs = rsqrtf(s2 * (1.0f / 128.0f) + LN_EPS);
#pragma unroll
            for (int c = 0; c < 8; c++) {
                int col = tx * 8 + c;
                v[c] = lng[col] * (v[c] - mu) * rs + lnb[col];
            }
        }
        float4* o = (float4*)(Xout + (size_t)grow * DIM + tx * 8);
        o[0] = make_float4(v[0], v[1], v[2], v[3]);
        o[1] = make_float4(v[4], v[5], v[6], v[7]);
    }
}

// ---- Global mean pool (partial sums) + head --------------------------------

__global__ __launch_bounds__(128) void pool_partial_kernel(const float* __restrict__ X,
                                                           const int* __restrict__ batch,
                                                           float* __restrict__ gsum) {
    int g = blockIdx.x;
    int s = blockIdx.y;
    int lo = lower_bound_i(batch, N_NODES, g);
    int hi = lower_bound_i(batch, N_NODES, g + 1);
    int len = hi - lo;
    int a = lo + (int)(((long long)len * s) / 8);
    int b = lo + (int)(((long long)len * (s + 1)) / 8);
    int c = threadIdx.x;
    float acc = 0.f;
    for (int n = a; n < b; n++) acc += X[(size_t)n * DIM + c];
    if (b > a) atomicAdd(&gsum[g * DIM + c], acc);
}

__global__ __launch_bounds__(128) void head_kernel(
    const float* __restrict__ gsum, const int* __restrict__ batch,
    const float* __restrict__ W1, const float* __restrict__ b1,
    const float* __restrict__ W2, const float* __restrict__ b2,
    float* __restrict__ out) {
    __shared__ float p[128];
    __shared__ float hh[128];
    int g = blockIdx.x;
    int j = threadIdx.x;
    int lo = lower_bound_i(batch, N_NODES, g);
    int hi = lower_bound_i(batch, N_NODES, g + 1);
    float cnt = fmaxf((float)(hi - lo), 1.0f);
    p[j] = gsum[g * DIM + j] / cnt;
    __syncthreads();
    float s = b1[j];
    for (int k = 0; k < DIM; k++) s += p[k] * W1[k * DIM + j];
    hh[j] = s;
    __syncthreads();
    if (j < CLS) {
        float l = b2[j];
        for (int k = 0; k < DIM; k++) l += hh[k] * W2[k * CLS + j];
        float mx = l;
#pragma unroll
        for (int m = 16; m >= 1; m >>= 1) mx = fmaxf(mx, __shfl_xor(mx, m, 64));
        float ex = expf(l - mx);
        float se = ex;
#pragma unroll
        for (int m = 16; m >= 1; m >>= 1) se += __shfl_xor(se, m, 64);
        out[g * CLS + j] = l - mx - logf(se);
    }
}

// ---- launch ----------------------------------------------------------------

extern "C" void kernel_launch(void* const* d_in, const int* in_sizes, int n_in,
                              void* d_out, int out_size, void* d_ws, size_t ws_size,
                              hipStream_t stream) {
    (void)in_sizes; (void)n_in; (void)out_size; (void)ws_size;
    const float* x     = (const float*)d_in[0];
    const float* Wself = (const float*)d_in[1];
    const float* bself = (const float*)d_in[2];
    const float* Wmsg  = (const float*)d_in[3];
    const float* bmsg  = (const float*)d_in[4];
    const float* lng   = (const float*)d_in[5];
    const float* lnb   = (const float*)d_in[6];
    const float* W1    = (const float*)d_in[7];
    const float* b1    = (const float*)d_in[8];
    const float* W2    = (const float*)d_in[9];
    const float* b2    = (const float*)d_in[10];
    const int*   ei    = (const int*)d_in[11];
    const int*   batch = (const int*)d_in[12];
    const int* esrc = ei;
    const int* edst = ei + N_EDGES;

    char* w = (char*)d_ws;
    size_t o = 0;
    auto alloc = [&](size_t bytes) { void* p = w + o; o += (bytes + 255) & ~(size_t)255; return p; };
    float* S      = (float*)alloc((size_t)N_NODES * DIM * 4);
    float* X0     = (float*)alloc((size_t)N_NODES * DIM * 4);
    float* X1     = (float*)alloc((size_t)N_NODES * DIM * 4);
    int*   counts = (int*)alloc((size_t)N_NODES * 4);
    int*   offs   = (int*)alloc((size_t)(N_NODES + 1) * 4);
    int*   csr    = (int*)alloc((size_t)N_EDGES * 4);
    float* gsum   = (float*)alloc((size_t)NGRAPH * DIM * 4);

    // CSR build (edge_index is constant, but rebuilt each call — same work every call)
    hipMemsetAsync(counts, 0, (size_t)N_NODES * 4, stream);
    hist_kernel<<<(N_EDGES + 255) / 256, 256, 0, stream>>>(edst, counts);
    scan_kernel<<<1, 1024, 0, stream>>>(counts, offs);
    hipMemsetAsync(counts, 0, (size_t)N_NODES * 4, stream);
    fill_csr_kernel<<<(N_EDGES + 255) / 256, 256, 0, stream>>>(esrc, edst, offs, counts, csr);

    const float* Xin = x;
    float* bufs[3] = {X0, X1, X0};
    for (int i = 0; i < 3; i++) {
        agg_kernel<<<(N_NODES + 3) / 4, 256, 0, stream>>>(Xin, offs, csr, S);
        layer_kernel<<<(N_NODES + 63) / 64, 256, 0, stream>>>(
            Xin, S,
            Wself + (size_t)i * DIM * DIM, Wmsg + (size_t)i * DIM * DIM,
            bself + i * DIM, bmsg + i * DIM, offs,
            (i < 2) ? lng + i * DIM : lng, (i < 2) ? lnb + i * DIM : lnb,
            bufs[i], (i < 2) ? 1 : 0);
        Xin = bufs[i];
    }

    hipMemsetAsync(gsum, 0, (size_t)NGRAPH * DIM * 4, stream);
    pool_partial_kernel<<<dim3(NGRAPH, 8), 128, 0, stream>>>(Xin, batch, gsum);
    head_kernel<<<NGRAPH, 128, 0, stream>>>(gsum, batch, W1, b1, W2, b2, (float*)d_out);
}

// Round 2
// 628.400 us; speedup vs baseline: 1.2497x; 1.2497x over previous
//
#include <hip/hip_runtime.h>
#include <hip/hip_bf16.h>
#include <math.h>

#define N_NODES 50000
#define N_EDGES 800000
#define DIM 128
#define CLS 32
#define NGRAPH 64
#define LN_EPS 1e-5f
// padded CSR capacity: sum ceil(deg/8)*8 <= E + 7*N
#define CSR_CAP (N_EDGES + 8 * N_NODES)

static __device__ __forceinline__ int lower_bound_i(const int* a, int n, int key) {
    int lo = 0, hi = n;
    while (lo < hi) { int mid = (lo + hi) >> 1; if (a[mid] < key) lo = mid + 1; else hi = mid; }
    return lo;
}

// ---- CSR build (dst-bucketed, padded to multiple of 8 per node) ------------

__global__ void hist_kernel(const int* __restrict__ dst, int* __restrict__ cnt) {
    int e = blockIdx.x * blockDim.x + threadIdx.x;
    if (e < N_EDGES) atomicAdd(&cnt[dst[e]], 1);
}

__global__ __launch_bounds__(1024) void scan_kernel(const int* __restrict__ cnt,
                                                    int* __restrict__ off) {
    __shared__ int sd[1024];
    const int ITEMS = (N_NODES + 1023) / 1024;  // 49
    int i = threadIdx.x;
    int begin = i * ITEMS;
    int end = min(begin + ITEMS, N_NODES);
    int t = 0;
    for (int j = begin; j < end; j++) t += (cnt[j] + 7) & ~7;  // padded sizes
    sd[i] = t;
    __syncthreads();
    for (int o = 1; o < 1024; o <<= 1) {
        int v = (i >= o) ? sd[i - o] : 0;
        __syncthreads();
        sd[i] += v;
        __syncthreads();
    }
    int base = sd[i] - t;  // exclusive prefix
    for (int j = begin; j < end; j++) { off[j] = base; base += (cnt[j] + 7) & ~7; }
    if (i == 1023) off[N_NODES] = sd[1023];
}

__global__ void init_csr_kernel(int* __restrict__ csr) {
    int i = blockIdx.x * blockDim.x + threadIdx.x;
    if (i < CSR_CAP) csr[i] = N_NODES;  // pad entries point at the zero row
}

__global__ void fill_csr_kernel(const int* __restrict__ src, const int* __restrict__ dst,
                                const int* __restrict__ off, int* __restrict__ cursor,
                                int* __restrict__ csr_src) {
    int e = blockIdx.x * blockDim.x + threadIdx.x;
    if (e < N_EDGES) {
        int d = dst[e];
        int pos = atomicAdd(&cursor[d], 1);
        csr_src[off[d] + pos] = src[e];
    }
}

// ---- fp32 -> bf16 shadow copy ----------------------------------------------

__global__ void f32_to_bf16_kernel(const float* __restrict__ in,
                                   __hip_bfloat16* __restrict__ out) {
    int i = blockIdx.x * blockDim.x + threadIdx.x;  // per 2 elements
    if (i < N_NODES * DIM / 2) {
        float2 v = ((const float2*)in)[i];
        ((__hip_bfloat162*)out)[i] = __float22bfloat162_rn(v);
    }
}

// ---- Neighbor sum: S[n,:] = sum_{e in CSR[n]} Xb[src[e],:]  (bf16 gather) --
// One wave per node; 8 independent gathers in flight; fp32 accumulate.

__global__ __launch_bounds__(256) void agg_kernel(const __hip_bfloat16* __restrict__ Xb,
                                                  const int* __restrict__ off,
                                                  const int* __restrict__ csr,
                                                  float* __restrict__ S) {
    int wave = threadIdx.x >> 6;
    int lane = threadIdx.x & 63;
    int n = blockIdx.x * 4 + wave;
    if (n >= N_NODES) return;
    int b = off[n], e = off[n + 1];  // padded: (e-b) % 8 == 0
    float ax = 0.f, ay = 0.f;
    const size_t coloff = (size_t)(lane * 2);
    for (int base = b; base < e; base += 8) {
        int idx8 = csr[base + (lane & 7)];
        int s[8];
        unsigned int v[8];
#pragma unroll
        for (int j = 0; j < 8; j++) s[j] = __shfl(idx8, j, 64);
#pragma unroll
        for (int j = 0; j < 8; j++)
            v[j] = *(const unsigned int*)(Xb + (size_t)s[j] * DIM + coloff);
#pragma unroll
        for (int j = 0; j < 8; j++) {
            union { unsigned int u; float f; } lo, hi;
            lo.u = v[j] << 16;             // bf16 element 0 (low address)
            hi.u = v[j] & 0xffff0000u;     // bf16 element 1
            ax += lo.f;
            ay += hi.f;
        }
    }
    ((float2*)(S + (size_t)n * DIM))[lane] = make_float2(ax, ay);
}

// ---- Fused layer: Xout = f(X@Wself + S@Wmsg + bself + deg*bmsg) ------------
// f = ReLU then optional LayerNorm. 64 rows x 128 cols per block.

__global__ __launch_bounds__(256) void layer_kernel(
    const float* __restrict__ X, const float* __restrict__ S,
    const float* __restrict__ Wself, const float* __restrict__ Wmsg,
    const float* __restrict__ bself, const float* __restrict__ bmsg,
    const int* __restrict__ deg,
    const float* __restrict__ lng, const float* __restrict__ lnb,
    float* __restrict__ Xout, __hip_bfloat16* __restrict__ XoutB, int do_ln) {
    __shared__ __align__(16) float at[128][68];  // [k][row]
    const int tx = threadIdx.x & 15;   // col group: cols tx*8 .. tx*8+7
    const int ty = threadIdx.x >> 4;   // row group: rows ty*4 .. ty*4+3
    const int row0 = blockIdx.x * 64;

    float acc[4][8];
#pragma unroll
    for (int r = 0; r < 4; r++)
#pragma unroll
        for (int c = 0; c < 8; c++) acc[r][c] = 0.f;

    for (int phase = 0; phase < 2; phase++) {
        const float* A = phase ? S : X;
        const float* W = phase ? Wmsg : Wself;
        __syncthreads();
#pragma unroll
        for (int i = 0; i < 8; i++) {
            int f = threadIdx.x + i * 256;  // float4 index 0..2047
            int row = f >> 5;               // 0..63
            int c4 = f & 31;
            int grow = row0 + row;
            float4 v = make_float4(0.f, 0.f, 0.f, 0.f);
            if (grow < N_NODES) v = *(const float4*)(A + (size_t)grow * DIM + c4 * 4);
            at[c4 * 4 + 0][row] = v.x;
            at[c4 * 4 + 1][row] = v.y;
            at[c4 * 4 + 2][row] = v.z;
            at[c4 * 4 + 3][row] = v.w;
        }
        __syncthreads();
        const float* wp = W + tx * 8;
#pragma unroll 4
        for (int k = 0; k < 128; k++) {
            float4 a4 = *(const float4*)&at[k][ty * 4];
            float4 w0 = *(const float4*)(wp + k * DIM);
            float4 w1 = *(const float4*)(wp + k * DIM + 4);
            float av[4] = {a4.x, a4.y, a4.z, a4.w};
            float wv[8] = {w0.x, w0.y, w0.z, w0.w, w1.x, w1.y, w1.z, w1.w};
#pragma unroll
            for (int r = 0; r < 4; r++)
#pragma unroll
                for (int c = 0; c < 8; c++) acc[r][c] += av[r] * wv[c];
        }
    }

#pragma unroll
    for (int r = 0; r < 4; r++) {
        int grow = row0 + ty * 4 + r;
        if (grow >= N_NODES) continue;
        float degf = (float)deg[grow];
        float v[8];
        float s1 = 0.f;
#pragma unroll
        for (int c = 0; c < 8; c++) {
            int col = tx * 8 + c;
            float h = acc[r][c] + bself[col] + degf * bmsg[col];
            h = fmaxf(h, 0.f);
            v[c] = h;
            s1 += h;
        }
        if (do_ln) {
#pragma unroll
            for (int m = 1; m < 16; m <<= 1) s1 += __shfl_xor(s1, m, 64);
            float mu = s1 * (1.0f / 128.0f);
            float s2 = 0.f;
#pragma unroll
            for (int c = 0; c < 8; c++) { float d = v[c] - mu; s2 += d * d; }
#pragma unroll
            for (int m = 1; m < 16; m <<= 1) s2 += __shfl_xor(s2, m, 64);
            float rs = rsqrtf(s2 * (1.0f / 128.0f) + LN_EPS);
#pragma unroll
            for (int c = 0; c < 8; c++) {
                int col = tx * 8 + c;
                v[c] = lng[col] * (v[c] - mu) * rs + lnb[col];
            }
        }
        float4* o = (float4*)(Xout + (size_t)grow * DIM + tx * 8);
        o[0] = make_float4(v[0], v[1], v[2], v[3]);
        o[1] = make_float4(v[4], v[5], v[6], v[7]);
        if (XoutB) {
            union { uint4 u; __hip_bfloat162 h[4]; } pk;
#pragma unroll
            for (int c2 = 0; c2 < 4; c2++)
                pk.h[c2] = __float22bfloat162_rn(make_float2(v[2 * c2], v[2 * c2 + 1]));
            *(uint4*)(XoutB + (size_t)grow * DIM + tx * 8) = pk.u;
        }
    }
}

// ---- Global mean pool (partial sums) + head --------------------------------

__global__ __launch_bounds__(128) void pool_partial_kernel(const float* __restrict__ X,
                                                           const int* __restrict__ batch,
                                                           float* __restrict__ gsum) {
    int g = blockIdx.x;
    int s = blockIdx.y;
    int lo = lower_bound_i(batch, N_NODES, g);
    int hi = lower_bound_i(batch, N_NODES, g + 1);
    int len = hi - lo;
    int a = lo + (int)(((long long)len * s) / 8);
    int b = lo + (int)(((long long)len * (s + 1)) / 8);
    int c = threadIdx.x;
    float acc = 0.f;
    for (int n = a; n < b; n++) acc += X[(size_t)n * DIM + c];
    if (b > a) atomicAdd(&gsum[g * DIM + c], acc);
}

__global__ __launch_bounds__(128) void head_kernel(
    const float* __restrict__ gsum, const int* __restrict__ batch,
    const float* __restrict__ W1, const float* __restrict__ b1,
    const float* __restrict__ W2, const float* __restrict__ b2,
    float* __restrict__ out) {
    __shared__ float p[128];
    __shared__ float hh[128];
    int g = blockIdx.x;
    int j = threadIdx.x;
    int lo = lower_bound_i(batch, N_NODES, g);
    int hi = lower_bound_i(batch, N_NODES, g + 1);
    float cnt = fmaxf((float)(hi - lo), 1.0f);
    p[j] = gsum[g * DIM + j] / cnt;
    __syncthreads();
    float s = b1[j];
    for (int k = 0; k < DIM; k++) s += p[k] * W1[k * DIM + j];
    hh[j] = s;
    __syncthreads();
    if (j < CLS) {
        float l = b2[j];
        for (int k = 0; k < DIM; k++) l += hh[k] * W2[k * CLS + j];
        float mx = l;
#pragma unroll
        for (int m = 16; m >= 1; m >>= 1) mx = fmaxf(mx, __shfl_xor(mx, m, 64));
        float ex = expf(l - mx);
        float se = ex;
#pragma unroll
        for (int m = 16; m >= 1; m >>= 1) se += __shfl_xor(se, m, 64);
        out[g * CLS + j] = l - mx - logf(se);
    }
}

// ---- launch ----------------------------------------------------------------

extern "C" void kernel_launch(void* const* d_in, const int* in_sizes, int n_in,
                              void* d_out, int out_size, void* d_ws, size_t ws_size,
                              hipStream_t stream) {
    (void)in_sizes; (void)n_in; (void)out_size; (void)ws_size;
    const float* x     = (const float*)d_in[0];
    const float* Wself = (const float*)d_in[1];
    const float* bself = (const float*)d_in[2];
    const float* Wmsg  = (const float*)d_in[3];
    const float* bmsg  = (const float*)d_in[4];
    const float* lng   = (const float*)d_in[5];
    const float* lnb   = (const float*)d_in[6];
    const float* W1    = (const float*)d_in[7];
    const float* b1    = (const float*)d_in[8];
    const float* W2    = (const float*)d_in[9];
    const float* b2    = (const float*)d_in[10];
    const int*   ei    = (const int*)d_in[11];
    const int*   batch = (const int*)d_in[12];
    const int* esrc = ei;
    const int* edst = ei + N_EDGES;

    char* w = (char*)d_ws;
    size_t o = 0;
    auto alloc = [&](size_t bytes) { void* p = w + o; o += (bytes + 255) & ~(size_t)255; return p; };
    float* S      = (float*)alloc((size_t)N_NODES * DIM * 4);
    float* X0     = (float*)alloc((size_t)N_NODES * DIM * 4);
    float* X1     = (float*)alloc((size_t)N_NODES * DIM * 4);
    __hip_bfloat16* XbIn = (__hip_bfloat16*)alloc((size_t)(N_NODES + 1) * DIM * 2);
    __hip_bfloat16* Xb0  = (__hip_bfloat16*)alloc((size_t)(N_NODES + 1) * DIM * 2);
    __hip_bfloat16* Xb1  = (__hip_bfloat16*)alloc((size_t)(N_NODES + 1) * DIM * 2);
    int*   counts = (int*)alloc((size_t)N_NODES * 4);
    int*   cursor = (int*)alloc((size_t)N_NODES * 4);
    int*   offs   = (int*)alloc((size_t)(N_NODES + 1) * 4);
    int*   csr    = (int*)alloc((size_t)CSR_CAP * 4);
    float* gsum   = (float*)alloc((size_t)NGRAPH * DIM * 4);

    // CSR build (padded to 8 per node; pad slots -> zero row N_NODES)
    hipMemsetAsync(counts, 0, (size_t)N_NODES * 4, stream);
    hipMemsetAsync(cursor, 0, (size_t)N_NODES * 4, stream);
    hist_kernel<<<(N_EDGES + 255) / 256, 256, 0, stream>>>(edst, counts);
    scan_kernel<<<1, 1024, 0, stream>>>(counts, offs);
    init_csr_kernel<<<(CSR_CAP + 255) / 256, 256, 0, stream>>>(csr);
    fill_csr_kernel<<<(N_EDGES + 255) / 256, 256, 0, stream>>>(esrc, edst, offs, cursor, csr);

    // bf16 shadow of input + zero pad rows of all bf16 buffers
    f32_to_bf16_kernel<<<(N_NODES * DIM / 2 + 255) / 256, 256, 0, stream>>>(x, XbIn);
    hipMemsetAsync(XbIn + (size_t)N_NODES * DIM, 0, DIM * 2, stream);
    hipMemsetAsync(Xb0 + (size_t)N_NODES * DIM, 0, DIM * 2, stream);
    hipMemsetAsync(Xb1 + (size_t)N_NODES * DIM, 0, DIM * 2, stream);

    const float* Xin = x;
    const __hip_bfloat16* XbCur = XbIn;
    float* bufs[3] = {X0, X1, X0};
    __hip_bfloat16* bbufs[3] = {Xb0, Xb1, nullptr};
    for (int i = 0; i < 3; i++) {
        agg_kernel<<<(N_NODES + 3) / 4, 256, 0, stream>>>(XbCur, offs, csr, S);
        layer_kernel<<<(N_NODES + 63) / 64, 256, 0, stream>>>(
            Xin, S,
            Wself + (size_t)i * DIM * DIM, Wmsg + (size_t)i * DIM * DIM,
            bself + i * DIM, bmsg + i * DIM, counts,
            (i < 2) ? lng + i * DIM : lng, (i < 2) ? lnb + i * DIM : lnb,
            bufs[i], bbufs[i], (i < 2) ? 1 : 0);
        Xin = bufs[i];
        XbCur = bbufs[i];
    }

    hipMemsetAsync(gsum, 0, (size_t)NGRAPH * DIM * 4, stream);
    pool_partial_kernel<<<dim3(NGRAPH, 8), 128, 0, stream>>>(Xin, batch, gsum);
    head_kernel<<<NGRAPH, 128, 0, stream>>>(gsum, batch, W1, b1, W2, b2, (float*)d_out);
}

// Round 4
// 450.042 us; speedup vs baseline: 1.7449x; 1.3963x over previous
//
#include <hip/hip_runtime.h>
#include <hip/hip_bf16.h>
#include <math.h>

#define N_NODES 50000
#define N_EDGES 800000
#define DIM 128
#define CLS 32
#define NGRAPH 64
#define LN_EPS 1e-5f
// padded CSR capacity: sum ceil(deg/8)*8 <= E + 7*N
#define CSR_CAP (N_EDGES + 8 * N_NODES)

typedef __attribute__((ext_vector_type(8))) short bf16x8;
typedef __attribute__((ext_vector_type(4))) float f32x4;

static __device__ __forceinline__ int lower_bound_i(const int* a, int n, int key) {
    int lo = 0, hi = n;
    while (lo < hi) { int mid = (lo + hi) >> 1; if (a[mid] < key) lo = mid + 1; else hi = mid; }
    return lo;
}

// ---- CSR build (dst-bucketed, padded to multiple of 8 per node) ------------

__global__ void hist_kernel(const int* __restrict__ dst, int* __restrict__ cnt) {
    int e = blockIdx.x * blockDim.x + threadIdx.x;
    if (e < N_EDGES) atomicAdd(&cnt[dst[e]], 1);
}

__global__ __launch_bounds__(1024) void scan_kernel(const int* __restrict__ cnt,
                                                    int* __restrict__ off) {
    __shared__ int sd[1024];
    const int ITEMS = (N_NODES + 1023) / 1024;  // 49
    int i = threadIdx.x;
    int begin = i * ITEMS;
    int end = min(begin + ITEMS, N_NODES);
    int t = 0;
    for (int j = begin; j < end; j++) t += (cnt[j] + 7) & ~7;  // padded sizes
    sd[i] = t;
    __syncthreads();
    for (int o = 1; o < 1024; o <<= 1) {
        int v = (i >= o) ? sd[i - o] : 0;
        __syncthreads();
        sd[i] += v;
        __syncthreads();
    }
    int base = sd[i] - t;  // exclusive prefix
    for (int j = begin; j < end; j++) { off[j] = base; base += (cnt[j] + 7) & ~7; }
    if (i == 1023) off[N_NODES] = sd[1023];
}

__global__ void init_csr_kernel(int* __restrict__ csr) {
    int i = blockIdx.x * blockDim.x + threadIdx.x;
    if (i < CSR_CAP) csr[i] = N_NODES;  // pad entries point at the zero row
}

__global__ void fill_csr_kernel(const int* __restrict__ src, const int* __restrict__ dst,
                                const int* __restrict__ off, int* __restrict__ cursor,
                                int* __restrict__ csr_src) {
    int e = blockIdx.x * blockDim.x + threadIdx.x;
    if (e < N_EDGES) {
        int d = dst[e];
        int pos = atomicAdd(&cursor[d], 1);
        csr_src[off[d] + pos] = src[e];
    }
}

// ---- weight prep: WT[l][n][k] bf16, k<128 -> Wself[l][k][n], else Wmsg -----

__global__ void prep_w_kernel(const float* __restrict__ Wself,
                              const float* __restrict__ Wmsg,
                              __hip_bfloat16* __restrict__ WT) {
    int i = blockIdx.x * blockDim.x + threadIdx.x;
    if (i >= 3 * 128 * 256) return;
    int l = i / (128 * 256);
    int rem = i - l * (128 * 256);
    int n = rem >> 8;
    int k = rem & 255;
    float v = (k < 128) ? Wself[l * 16384 + k * 128 + n]
                        : Wmsg[l * 16384 + (k - 128) * 128 + n];
    WT[i] = __float2bfloat16(v);
}

// ---- fp32 -> bf16 shadow copy ----------------------------------------------

__global__ void f32_to_bf16_kernel(const float* __restrict__ in,
                                   __hip_bfloat16* __restrict__ out) {
    int i = blockIdx.x * blockDim.x + threadIdx.x;  // per 2 elements
    if (i < N_NODES * DIM / 2) {
        float2 v = ((const float2*)in)[i];
        ((__hip_bfloat162*)out)[i] = __float22bfloat162_rn(v);
    }
}

// ---- Neighbor sum: Sb[n,:] = sum_{e in CSR[n]} Xb[src[e],:] (bf16 in/out) --

__global__ __launch_bounds__(256) void agg_kernel(const __hip_bfloat16* __restrict__ Xb,
                                                  const int* __restrict__ off,
                                                  const int* __restrict__ csr,
                                                  __hip_bfloat16* __restrict__ Sb) {
    int wave = threadIdx.x >> 6;
    int lane = threadIdx.x & 63;
    int n = blockIdx.x * 4 + wave;
    if (n >= N_NODES) return;
    int b = off[n], e = off[n + 1];  // padded: (e-b) % 8 == 0
    float ax = 0.f, ay = 0.f;
    const size_t coloff = (size_t)(lane * 2);
    for (int base = b; base < e; base += 8) {
        int idx8 = csr[base + (lane & 7)];
        int s[8];
        unsigned int v[8];
#pragma unroll
        for (int j = 0; j < 8; j++) s[j] = __shfl(idx8, j, 64);
#pragma unroll
        for (int j = 0; j < 8; j++)
            v[j] = *(const unsigned int*)(Xb + (size_t)s[j] * DIM + coloff);
#pragma unroll
        for (int j = 0; j < 8; j++) {
            union { unsigned int u; float f; } lo, hi;
            lo.u = v[j] << 16;             // bf16 element 0 (low address)
            hi.u = v[j] & 0xffff0000u;     // bf16 element 1
            ax += lo.f;
            ay += hi.f;
        }
    }
    ((__hip_bfloat162*)(Sb + (size_t)n * DIM))[lane] =
        __float22bfloat162_rn(make_float2(ax, ay));
}

// ---- Fused layer via MFMA: H = [Xb|Sb] @ WT^T; +bias+deg*bmsg, ReLU, LN ----
// Block: 256 threads = 4 waves; each wave: 16 rows x 128 cols, K=256 in two
// 128-chunks (chunk 0: Xb@Wself, chunk 1: Sb@Wmsg). A-frags direct from global
// (row-clamped to zero pad row). W chunk staged in LDS (128 rows x 128 k).

__global__ __launch_bounds__(256) void layer_mfma_kernel(
    const __hip_bfloat16* __restrict__ Xb, const __hip_bfloat16* __restrict__ Sb,
    const __hip_bfloat16* __restrict__ WT,  // [128 n][256 k] bf16 for this layer
    const float* __restrict__ bself, const float* __restrict__ bmsg,
    const int* __restrict__ deg,
    const float* __restrict__ lng, const float* __restrict__ lnb,
    __hip_bfloat16* __restrict__ XoutB, int do_ln) {
    // stride 136 bf16 = 272 B (16B-aligned rows, 2-way bank aliasing = free)
    __shared__ __hip_bfloat16 wlds[128 * 136];
    const int tid = threadIdx.x;
    const int w = tid >> 6, lane = tid & 63;
    const int l15 = lane & 15, q = lane >> 4;

    const int row = blockIdx.x * 64 + w * 16 + l15;
    const int rowc = min(row, N_NODES);  // pad row N_NODES is all zeros

    f32x4 acc[8];
#pragma unroll
    for (int ct = 0; ct < 8; ct++) acc[ct] = (f32x4){0.f, 0.f, 0.f, 0.f};

    const __hip_bfloat16* Abase[2] = {Xb, Sb};
    for (int c = 0; c < 2; c++) {
        __syncthreads();  // protect previous chunk's LDS reads
        {
            // stage WT[n][c*128 .. c*128+127] -> wlds[n][0..127]
            // 256 threads x 8 uint4 (128 B) = 32 KB = 128 rows x 128 bf16
            int n = tid >> 1, h = tid & 1;
            const uint4* src = (const uint4*)(WT + n * 256 + c * 128 + h * 64);
            uint4* dst = (uint4*)(&wlds[n * 136 + h * 64]);
#pragma unroll
            for (int i = 0; i < 8; i++) dst[i] = src[i];
        }
        __syncthreads();
        const __hip_bfloat16* arow = Abase[c] + (size_t)rowc * DIM;
#pragma unroll
        for (int ks = 0; ks < 4; ks++) {
            bf16x8 afrag = *(const bf16x8*)(arow + ks * 32 + q * 8);
#pragma unroll
            for (int ct = 0; ct < 8; ct++) {
                bf16x8 bfrag = *(const bf16x8*)(&wlds[(ct * 16 + l15) * 136 + ks * 32 + q * 8]);
                acc[ct] = __builtin_amdgcn_mfma_f32_16x16x32_bf16(afrag, bfrag, acc[ct], 0, 0, 0);
            }
        }
    }

    // epilogue: lane holds rows (q*4+r), cols (ct*16+l15)
    const int growbase = blockIdx.x * 64 + w * 16;
#pragma unroll
    for (int r = 0; r < 4; r++) {
        int grow = growbase + q * 4 + r;
        bool valid = grow < N_NODES;
        float dg = valid ? (float)deg[grow] : 0.f;
        float v[8];
        float s1 = 0.f;
#pragma unroll
        for (int ct = 0; ct < 8; ct++) {
            int col = ct * 16 + l15;
            float h = acc[ct][r] + bself[col] + dg * bmsg[col];
            h = fmaxf(h, 0.f);
            v[ct] = h;
            s1 += h;
        }
        if (do_ln) {
#pragma unroll
            for (int m = 1; m < 16; m <<= 1) s1 += __shfl_xor(s1, m, 64);
            float mu = s1 * (1.0f / 128.0f);
            float s2 = 0.f;
#pragma unroll
            for (int ct = 0; ct < 8; ct++) { float d = v[ct] - mu; s2 += d * d; }
#pragma unroll
            for (int m = 1; m < 16; m <<= 1) s2 += __shfl_xor(s2, m, 64);
            float rs = rsqrtf(s2 * (1.0f / 128.0f) + LN_EPS);
#pragma unroll
            for (int ct = 0; ct < 8; ct++) {
                int col = ct * 16 + l15;
                v[ct] = lng[col] * (v[ct] - mu) * rs + lnb[col];
            }
        }
        if (valid) {
#pragma unroll
            for (int ct = 0; ct < 8; ct++) {
                int col = ct * 16 + l15;
                XoutB[(size_t)grow * DIM + col] = __float2bfloat16(v[ct]);
            }
        }
    }
}

// ---- Global mean pool (partial sums) + head --------------------------------

__global__ __launch_bounds__(128) void pool_partial_kernel(const __hip_bfloat16* __restrict__ X,
                                                           const int* __restrict__ batch,
                                                           float* __restrict__ gsum) {
    int g = blockIdx.x;
    int s = blockIdx.y;
    int lo = lower_bound_i(batch, N_NODES, g);
    int hi = lower_bound_i(batch, N_NODES, g + 1);
    int len = hi - lo;
    int a = lo + (int)(((long long)len * s) / 8);
    int b = lo + (int)(((long long)len * (s + 1)) / 8);
    int c = threadIdx.x;
    float acc = 0.f;
    for (int n = a; n < b; n++) acc += __bfloat162float(X[(size_t)n * DIM + c]);
    if (b > a) atomicAdd(&gsum[g * DIM + c], acc);
}

__global__ __launch_bounds__(128) void head_kernel(
    const float* __restrict__ gsum, const int* __restrict__ batch,
    const float* __restrict__ W1, const float* __restrict__ b1,
    const float* __restrict__ W2, const float* __restrict__ b2,
    float* __restrict__ out) {
    __shared__ float p[128];
    __shared__ float hh[128];
    int g = blockIdx.x;
    int j = threadIdx.x;
    int lo = lower_bound_i(batch, N_NODES, g);
    int hi = lower_bound_i(batch, N_NODES, g + 1);
    float cnt = fmaxf((float)(hi - lo), 1.0f);
    p[j] = gsum[g * DIM + j] / cnt;
    __syncthreads();
    float s = b1[j];
    for (int k = 0; k < DIM; k++) s += p[k] * W1[k * DIM + j];
    hh[j] = s;
    __syncthreads();
    if (j < CLS) {
        float l = b2[j];
        for (int k = 0; k < DIM; k++) l += hh[k] * W2[k * CLS + j];
        float mx = l;
#pragma unroll
        for (int m = 16; m >= 1; m >>= 1) mx = fmaxf(mx, __shfl_xor(mx, m, 64));
        float ex = expf(l - mx);
        float se = ex;
#pragma unroll
        for (int m = 16; m >= 1; m >>= 1) se += __shfl_xor(se, m, 64);
        out[g * CLS + j] = l - mx - logf(se);
    }
}

// ---- launch ----------------------------------------------------------------

extern "C" void kernel_launch(void* const* d_in, const int* in_sizes, int n_in,
                              void* d_out, int out_size, void* d_ws, size_t ws_size,
                              hipStream_t stream) {
    (void)in_sizes; (void)n_in; (void)out_size; (void)ws_size;
    const float* x     = (const float*)d_in[0];
    const float* Wself = (const float*)d_in[1];
    const float* bself = (const float*)d_in[2];
    const float* Wmsg  = (const float*)d_in[3];
    const float* bmsg  = (const float*)d_in[4];
    const float* lng   = (const float*)d_in[5];
    const float* lnb   = (const float*)d_in[6];
    const float* W1    = (const float*)d_in[7];
    const float* b1    = (const float*)d_in[8];
    const float* W2    = (const float*)d_in[9];
    const float* b2    = (const float*)d_in[10];
    const int*   ei    = (const int*)d_in[11];
    const int*   batch = (const int*)d_in[12];
    const int* esrc = ei;
    const int* edst = ei + N_EDGES;

    char* w = (char*)d_ws;
    size_t o = 0;
    auto alloc = [&](size_t bytes) { void* p = w + o; o += (bytes + 255) & ~(size_t)255; return p; };
    __hip_bfloat16* XbIn = (__hip_bfloat16*)alloc((size_t)(N_NODES + 1) * DIM * 2);
    __hip_bfloat16* Xb0  = (__hip_bfloat16*)alloc((size_t)(N_NODES + 1) * DIM * 2);
    __hip_bfloat16* Xb1  = (__hip_bfloat16*)alloc((size_t)(N_NODES + 1) * DIM * 2);
    __hip_bfloat16* Sb   = (__hip_bfloat16*)alloc((size_t)(N_NODES + 1) * DIM * 2);
    __hip_bfloat16* WT   = (__hip_bfloat16*)alloc((size_t)3 * 128 * 256 * 2);
    int*   counts = (int*)alloc((size_t)N_NODES * 4);
    int*   cursor = (int*)alloc((size_t)N_NODES * 4);
    int*   offs   = (int*)alloc((size_t)(N_NODES + 1) * 4);
    int*   csr    = (int*)alloc((size_t)CSR_CAP * 4);
    float* gsum   = (float*)alloc((size_t)NGRAPH * DIM * 4);

    // CSR build (padded to 8 per node; pad slots -> zero row N_NODES)
    hipMemsetAsync(counts, 0, (size_t)N_NODES * 4, stream);
    hipMemsetAsync(cursor, 0, (size_t)N_NODES * 4, stream);
    hist_kernel<<<(N_EDGES + 255) / 256, 256, 0, stream>>>(edst, counts);
    scan_kernel<<<1, 1024, 0, stream>>>(counts, offs);
    init_csr_kernel<<<(CSR_CAP + 255) / 256, 256, 0, stream>>>(csr);
    fill_csr_kernel<<<(N_EDGES + 255) / 256, 256, 0, stream>>>(esrc, edst, offs, cursor, csr);

    // weights -> bf16 transposed; input -> bf16; zero pad rows
    prep_w_kernel<<<(3 * 128 * 256 + 255) / 256, 256, 0, stream>>>(Wself, Wmsg, WT);
    f32_to_bf16_kernel<<<(N_NODES * DIM / 2 + 255) / 256, 256, 0, stream>>>(x, XbIn);
    hipMemsetAsync(XbIn + (size_t)N_NODES * DIM, 0, DIM * 2, stream);
    hipMemsetAsync(Xb0 + (size_t)N_NODES * DIM, 0, DIM * 2, stream);
    hipMemsetAsync(Xb1 + (size_t)N_NODES * DIM, 0, DIM * 2, stream);
    hipMemsetAsync(Sb + (size_t)N_NODES * DIM, 0, DIM * 2, stream);

    const __hip_bfloat16* XbCur = XbIn;
    __hip_bfloat16* bbufs[3] = {Xb0, Xb1, Xb0};
    for (int i = 0; i < 3; i++) {
        agg_kernel<<<(N_NODES + 3) / 4, 256, 0, stream>>>(XbCur, offs, csr, Sb);
        layer_mfma_kernel<<<(N_NODES + 63) / 64, 256, 0, stream>>>(
            XbCur, Sb, WT + (size_t)i * 128 * 256,
            bself + i * DIM, bmsg + i * DIM, counts,
            (i < 2) ? lng + i * DIM : lng, (i < 2) ? lnb + i * DIM : lnb,
            bbufs[i], (i < 2) ? 1 : 0);
        XbCur = bbufs[i];
    }

    hipMemsetAsync(gsum, 0, (size_t)NGRAPH * DIM * 4, stream);
    pool_partial_kernel<<<dim3(NGRAPH, 8), 128, 0, stream>>>(bbufs[2], batch, gsum);
    head_kernel<<<NGRAPH, 128, 0, stream>>>(gsum, batch, W1, b1, W2, b2, (float*)d_out);
}

// Round 5
// 384.039 us; speedup vs baseline: 2.0448x; 1.1719x over previous
//
#include <hip/hip_runtime.h>
#include <hip/hip_bf16.h>
#include <math.h>

#define N_NODES 50000
#define N_EDGES 800000
#define DIM 128
#define CLS 32
#define NGRAPH 64
#define LN_EPS 1e-5f
// padded CSR capacity: sum ceil(deg/8)*8 <= E + 7*N
#define CSR_CAP (N_EDGES + 8 * N_NODES)
#define NBLK ((N_NODES + 255) / 256)   // 196 scan blocks

typedef __attribute__((ext_vector_type(8))) short bf16x8;
typedef __attribute__((ext_vector_type(4))) float f32x4;

static __device__ __forceinline__ int lower_bound_i(const int* a, int n, int key) {
    int lo = 0, hi = n;
    while (lo < hi) { int mid = (lo + hi) >> 1; if (a[mid] < key) lo = mid + 1; else hi = mid; }
    return lo;
}

// ---- CSR build (dst-bucketed, padded to multiple of 8 per node) ------------

__global__ void hist_kernel(const int* __restrict__ dst, int* __restrict__ cnt) {
    int e = blockIdx.x * blockDim.x + threadIdx.x;
    if (e < N_EDGES) atomicAdd(&cnt[dst[e]], 1);
}

// hierarchical exclusive scan of padded counts, 3 stages, all parallel
__global__ __launch_bounds__(256) void scan_part1_kernel(const int* __restrict__ cnt,
                                                         int* __restrict__ bsum) {
    __shared__ int sd[256];
    int gi = blockIdx.x * 256 + threadIdx.x;
    int v = (gi < N_NODES) ? ((cnt[gi] + 7) & ~7) : 0;
    sd[threadIdx.x] = v;
    __syncthreads();
    for (int o = 128; o > 0; o >>= 1) {
        if (threadIdx.x < o) sd[threadIdx.x] += sd[threadIdx.x + o];
        __syncthreads();
    }
    if (threadIdx.x == 0) bsum[blockIdx.x] = sd[0];
}

__global__ __launch_bounds__(256) void scan_part2_kernel(int* __restrict__ bsum) {
    __shared__ int sd[256];
    int i = threadIdx.x;
    int v = (i < NBLK) ? bsum[i] : 0;
    sd[i] = v;
    __syncthreads();
    for (int o = 1; o < 256; o <<= 1) {
        int t = (i >= o) ? sd[i - o] : 0;
        __syncthreads();
        sd[i] += t;
        __syncthreads();
    }
    if (i < NBLK) bsum[i] = sd[i] - v;  // exclusive
}

__global__ __launch_bounds__(256) void scan_part3_kernel(const int* __restrict__ cnt,
                                                         const int* __restrict__ bsum,
                                                         int* __restrict__ off) {
    __shared__ int sd[256];
    int gi = blockIdx.x * 256 + threadIdx.x;
    int i = threadIdx.x;
    int v = (gi < N_NODES) ? ((cnt[gi] + 7) & ~7) : 0;
    sd[i] = v;
    __syncthreads();
    for (int o = 1; o < 256; o <<= 1) {
        int t = (i >= o) ? sd[i - o] : 0;
        __syncthreads();
        sd[i] += t;
        __syncthreads();
    }
    int incl = sd[i];
    int base = bsum[blockIdx.x];
    if (gi < N_NODES) off[gi] = base + incl - v;
    if (gi == N_NODES - 1) off[N_NODES] = base + incl;
}

__global__ void init_csr_kernel(int* __restrict__ csr) {
    int i = blockIdx.x * blockDim.x + threadIdx.x;
    if (i < CSR_CAP) csr[i] = N_NODES;  // pad entries point at the zero row
}

__global__ void fill_csr_kernel(const int* __restrict__ src, const int* __restrict__ dst,
                                const int* __restrict__ off, int* __restrict__ cursor,
                                int* __restrict__ csr_src) {
    int e = blockIdx.x * blockDim.x + threadIdx.x;
    if (e < N_EDGES) {
        int d = dst[e];
        int pos = atomicAdd(&cursor[d], 1);
        csr_src[off[d] + pos] = src[e];
    }
}

// ---- weight prep: WT[l][n][k] bf16, k<128 -> Wself[l][k][n], else Wmsg -----

__global__ void prep_w_kernel(const float* __restrict__ Wself,
                              const float* __restrict__ Wmsg,
                              __hip_bfloat16* __restrict__ WT) {
    int i = blockIdx.x * blockDim.x + threadIdx.x;
    if (i >= 3 * 128 * 256) return;
    int l = i / (128 * 256);
    int rem = i - l * (128 * 256);
    int n = rem >> 8;
    int k = rem & 255;
    float v = (k < 128) ? Wself[l * 16384 + k * 128 + n]
                        : Wmsg[l * 16384 + (k - 128) * 128 + n];
    WT[i] = __float2bfloat16(v);
}

// ---- fp32 -> bf16 shadow copy ----------------------------------------------

__global__ void f32_to_bf16_kernel(const float* __restrict__ in,
                                   __hip_bfloat16* __restrict__ out) {
    int i = blockIdx.x * blockDim.x + threadIdx.x;  // per 2 elements
    if (i < N_NODES * DIM / 2) {
        float2 v = ((const float2*)in)[i];
        ((__hip_bfloat162*)out)[i] = __float22bfloat162_rn(v);
    }
}

// ---- Neighbor sum: Sb[n,:] = sum_{e in CSR[n]} Xb[src[e],:] (bf16 in/out) --
// One wave per node; 16 independent gathers in flight (8-edge tail); fp32 acc.

__global__ __launch_bounds__(256) void agg_kernel(const __hip_bfloat16* __restrict__ Xb,
                                                  const int* __restrict__ off,
                                                  const int* __restrict__ csr,
                                                  __hip_bfloat16* __restrict__ Sb) {
    int wave = threadIdx.x >> 6;
    int lane = threadIdx.x & 63;
    int n = blockIdx.x * 4 + wave;
    if (n >= N_NODES) return;
    int b = off[n], e = off[n + 1];  // padded: (e-b) % 8 == 0
    float ax = 0.f, ay = 0.f;
    const size_t coloff = (size_t)(lane * 2);
    int base = b;
    for (; base + 16 <= e; base += 16) {
        int idx16 = csr[base + (lane & 15)];
        int s[16];
        unsigned int v[16];
#pragma unroll
        for (int j = 0; j < 16; j++) s[j] = __shfl(idx16, j, 64);
#pragma unroll
        for (int j = 0; j < 16; j++)
            v[j] = *(const unsigned int*)(Xb + (size_t)s[j] * DIM + coloff);
#pragma unroll
        for (int j = 0; j < 16; j++) {
            union { unsigned int u; float f; } lo, hi;
            lo.u = v[j] << 16;
            hi.u = v[j] & 0xffff0000u;
            ax += lo.f;
            ay += hi.f;
        }
    }
    if (base < e) {  // 8-edge tail
        int idx8 = csr[base + (lane & 7)];
        int s[8];
        unsigned int v[8];
#pragma unroll
        for (int j = 0; j < 8; j++) s[j] = __shfl(idx8, j, 64);
#pragma unroll
        for (int j = 0; j < 8; j++)
            v[j] = *(const unsigned int*)(Xb + (size_t)s[j] * DIM + coloff);
#pragma unroll
        for (int j = 0; j < 8; j++) {
            union { unsigned int u; float f; } lo, hi;
            lo.u = v[j] << 16;
            hi.u = v[j] & 0xffff0000u;
            ax += lo.f;
            ay += hi.f;
        }
    }
    ((__hip_bfloat162*)(Sb + (size_t)n * DIM))[lane] =
        __float22bfloat162_rn(make_float2(ax, ay));
}

// ---- Fused layer via MFMA: H = [Xb|Sb] @ WT^T; +bias+deg*bmsg, ReLU, LN ----

__global__ __launch_bounds__(256) void layer_mfma_kernel(
    const __hip_bfloat16* __restrict__ Xb, const __hip_bfloat16* __restrict__ Sb,
    const __hip_bfloat16* __restrict__ WT,  // [128 n][256 k] bf16 for this layer
    const float* __restrict__ bself, const float* __restrict__ bmsg,
    const int* __restrict__ deg,
    const float* __restrict__ lng, const float* __restrict__ lnb,
    __hip_bfloat16* __restrict__ XoutB, int do_ln) {
    // stride 136 bf16 = 272 B (16B-aligned rows, 2-way bank aliasing = free)
    __shared__ __hip_bfloat16 wlds[128 * 136];
    const int tid = threadIdx.x;
    const int w = tid >> 6, lane = tid & 63;
    const int l15 = lane & 15, q = lane >> 4;

    const int row = blockIdx.x * 64 + w * 16 + l15;
    const int rowc = min(row, N_NODES);  // pad row N_NODES is all zeros

    f32x4 acc[8];
#pragma unroll
    for (int ct = 0; ct < 8; ct++) acc[ct] = (f32x4){0.f, 0.f, 0.f, 0.f};

    const __hip_bfloat16* Abase[2] = {Xb, Sb};
    for (int c = 0; c < 2; c++) {
        __syncthreads();  // protect previous chunk's LDS reads
        {
            // stage WT[n][c*128 .. c*128+127] -> wlds[n][0..127]
            // 256 threads x 8 uint4 (128 B) = 32 KB = 128 rows x 128 bf16
            int n = tid >> 1, h = tid & 1;
            const uint4* src = (const uint4*)(WT + n * 256 + c * 128 + h * 64);
            uint4* dst = (uint4*)(&wlds[n * 136 + h * 64]);
#pragma unroll
            for (int i = 0; i < 8; i++) dst[i] = src[i];
        }
        __syncthreads();
        const __hip_bfloat16* arow = Abase[c] + (size_t)rowc * DIM;
#pragma unroll
        for (int ks = 0; ks < 4; ks++) {
            bf16x8 afrag = *(const bf16x8*)(arow + ks * 32 + q * 8);
#pragma unroll
            for (int ct = 0; ct < 8; ct++) {
                bf16x8 bfrag = *(const bf16x8*)(&wlds[(ct * 16 + l15) * 136 + ks * 32 + q * 8]);
                acc[ct] = __builtin_amdgcn_mfma_f32_16x16x32_bf16(afrag, bfrag, acc[ct], 0, 0, 0);
            }
        }
    }

    // epilogue: lane holds rows (q*4+r), cols (ct*16+l15)
    const int growbase = blockIdx.x * 64 + w * 16;
#pragma unroll
    for (int r = 0; r < 4; r++) {
        int grow = growbase + q * 4 + r;
        bool valid = grow < N_NODES;
        float dg = valid ? (float)deg[grow] : 0.f;
        float v[8];
        float s1 = 0.f;
#pragma unroll
        for (int ct = 0; ct < 8; ct++) {
            int col = ct * 16 + l15;
            float h = acc[ct][r] + bself[col] + dg * bmsg[col];
            h = fmaxf(h, 0.f);
            v[ct] = h;
            s1 += h;
        }
        if (do_ln) {
#pragma unroll
            for (int m = 1; m < 16; m <<= 1) s1 += __shfl_xor(s1, m, 64);
            float mu = s1 * (1.0f / 128.0f);
            float s2 = 0.f;
#pragma unroll
            for (int ct = 0; ct < 8; ct++) { float d = v[ct] - mu; s2 += d * d; }
#pragma unroll
            for (int m = 1; m < 16; m <<= 1) s2 += __shfl_xor(s2, m, 64);
            float rs = rsqrtf(s2 * (1.0f / 128.0f) + LN_EPS);
#pragma unroll
            for (int ct = 0; ct < 8; ct++) {
                int col = ct * 16 + l15;
                v[ct] = lng[col] * (v[ct] - mu) * rs + lnb[col];
            }
        }
        if (valid) {
#pragma unroll
            for (int ct = 0; ct < 8; ct++) {
                int col = ct * 16 + l15;
                XoutB[(size_t)grow * DIM + col] = __float2bfloat16(v[ct]);
            }
        }
    }
}

// ---- Global mean pool (partial sums) + head --------------------------------

__global__ __launch_bounds__(128) void pool_partial_kernel(const __hip_bfloat16* __restrict__ X,
                                                           const int* __restrict__ batch,
                                                           float* __restrict__ gsum) {
    int g = blockIdx.x;
    int s = blockIdx.y;
    int lo = lower_bound_i(batch, N_NODES, g);
    int hi = lower_bound_i(batch, N_NODES, g + 1);
    int len = hi - lo;
    int a = lo + (int)(((long long)len * s) / 8);
    int b = lo + (int)(((long long)len * (s + 1)) / 8);
    int c = threadIdx.x;
    float acc = 0.f;
    for (int n = a; n < b; n++) acc += __bfloat162float(X[(size_t)n * DIM + c]);
    if (b > a) atomicAdd(&gsum[g * DIM + c], acc);
}

__global__ __launch_bounds__(128) void head_kernel(
    const float* __restrict__ gsum, const int* __restrict__ batch,
    const float* __restrict__ W1, const float* __restrict__ b1,
    const float* __restrict__ W2, const float* __restrict__ b2,
    float* __restrict__ out) {
    __shared__ float p[128];
    __shared__ float hh[128];
    int g = blockIdx.x;
    int j = threadIdx.x;
    int lo = lower_bound_i(batch, N_NODES, g);
    int hi = lower_bound_i(batch, N_NODES, g + 1);
    float cnt = fmaxf((float)(hi - lo), 1.0f);
    p[j] = gsum[g * DIM + j] / cnt;
    __syncthreads();
    float s = b1[j];
    for (int k = 0; k < DIM; k++) s += p[k] * W1[k * DIM + j];
    hh[j] = s;
    __syncthreads();
    if (j < CLS) {
        float l = b2[j];
        for (int k = 0; k < DIM; k++) l += hh[k] * W2[k * CLS + j];
        float mx = l;
#pragma unroll
        for (int m = 16; m >= 1; m >>= 1) mx = fmaxf(mx, __shfl_xor(mx, m, 64));
        float ex = expf(l - mx);
        float se = ex;
#pragma unroll
        for (int m = 16; m >= 1; m >>= 1) se += __shfl_xor(se, m, 64);
        out[g * CLS + j] = l - mx - logf(se);
    }
}

// ---- launch ----------------------------------------------------------------

extern "C" void kernel_launch(void* const* d_in, const int* in_sizes, int n_in,
                              void* d_out, int out_size, void* d_ws, size_t ws_size,
                              hipStream_t stream) {
    (void)in_sizes; (void)n_in; (void)out_size; (void)ws_size;
    const float* x     = (const float*)d_in[0];
    const float* Wself = (const float*)d_in[1];
    const float* bself = (const float*)d_in[2];
    const float* Wmsg  = (const float*)d_in[3];
    const float* bmsg  = (const float*)d_in[4];
    const float* lng   = (const float*)d_in[5];
    const float* lnb   = (const float*)d_in[6];
    const float* W1    = (const float*)d_in[7];
    const float* b1    = (const float*)d_in[8];
    const float* W2    = (const float*)d_in[9];
    const float* b2    = (const float*)d_in[10];
    const int*   ei    = (const int*)d_in[11];
    const int*   batch = (const int*)d_in[12];
    const int* esrc = ei;
    const int* edst = ei + N_EDGES;

    char* w = (char*)d_ws;
    size_t o = 0;
    auto alloc = [&](size_t bytes) { void* p = w + o; o += (bytes + 255) & ~(size_t)255; return p; };
    __hip_bfloat16* XbIn = (__hip_bfloat16*)alloc((size_t)(N_NODES + 1) * DIM * 2);
    __hip_bfloat16* Xb0  = (__hip_bfloat16*)alloc((size_t)(N_NODES + 1) * DIM * 2);
    __hip_bfloat16* Xb1  = (__hip_bfloat16*)alloc((size_t)(N_NODES + 1) * DIM * 2);
    __hip_bfloat16* Sb   = (__hip_bfloat16*)alloc((size_t)(N_NODES + 1) * DIM * 2);
    __hip_bfloat16* WT   = (__hip_bfloat16*)alloc((size_t)3 * 128 * 256 * 2);
    int*   counts = (int*)alloc((size_t)N_NODES * 4);
    int*   cursor = (int*)alloc((size_t)N_NODES * 4);
    int*   offs   = (int*)alloc((size_t)(N_NODES + 1) * 4);
    int*   bsum   = (int*)alloc((size_t)NBLK * 4);
    int*   csr    = (int*)alloc((size_t)CSR_CAP * 4);
    float* gsum   = (float*)alloc((size_t)NGRAPH * DIM * 4);

    // CSR build (padded to 8 per node; pad slots -> zero row N_NODES)
    hipMemsetAsync(counts, 0, (size_t)N_NODES * 4, stream);
    hipMemsetAsync(cursor, 0, (size_t)N_NODES * 4, stream);
    hist_kernel<<<(N_EDGES + 255) / 256, 256, 0, stream>>>(edst, counts);
    scan_part1_kernel<<<NBLK, 256, 0, stream>>>(counts, bsum);
    scan_part2_kernel<<<1, 256, 0, stream>>>(bsum);
    scan_part3_kernel<<<NBLK, 256, 0, stream>>>(counts, bsum, offs);
    init_csr_kernel<<<(CSR_CAP + 255) / 256, 256, 0, stream>>>(csr);
    fill_csr_kernel<<<(N_EDGES + 255) / 256, 256, 0, stream>>>(esrc, edst, offs, cursor, csr);

    // weights -> bf16 transposed; input -> bf16; zero pad rows
    prep_w_kernel<<<(3 * 128 * 256 + 255) / 256, 256, 0, stream>>>(Wself, Wmsg, WT);
    f32_to_bf16_kernel<<<(N_NODES * DIM / 2 + 255) / 256, 256, 0, stream>>>(x, XbIn);
    hipMemsetAsync(XbIn + (size_t)N_NODES * DIM, 0, DIM * 2, stream);
    hipMemsetAsync(Xb0 + (size_t)N_NODES * DIM, 0, DIM * 2, stream);
    hipMemsetAsync(Xb1 + (size_t)N_NODES * DIM, 0, DIM * 2, stream);
    hipMemsetAsync(Sb + (size_t)N_NODES * DIM, 0, DIM * 2, stream);

    const __hip_bfloat16* XbCur = XbIn;
    __hip_bfloat16* bbufs[3] = {Xb0, Xb1, Xb0};
    for (int i = 0; i < 3; i++) {
        agg_kernel<<<(N_NODES + 3) / 4, 256, 0, stream>>>(XbCur, offs, csr, Sb);
        layer_mfma_kernel<<<(N_NODES + 63) / 64, 256, 0, stream>>>(
            XbCur, Sb, WT + (size_t)i * 128 * 256,
            bself + i * DIM, bmsg + i * DIM, counts,
            (i < 2) ? lng + i * DIM : lng, (i < 2) ? lnb + i * DIM : lnb,
            bbufs[i], (i < 2) ? 1 : 0);
        XbCur = bbufs[i];
    }

    hipMemsetAsync(gsum, 0, (size_t)NGRAPH * DIM * 4, stream);
    pool_partial_kernel<<<dim3(NGRAPH, 8), 128, 0, stream>>>(bbufs[2], batch, gsum);
    head_kernel<<<NGRAPH, 128, 0, stream>>>(gsum, batch, W1, b1, W2, b2, (float*)d_out);
}

// Round 6
// 375.196 us; speedup vs baseline: 2.0930x; 1.0236x over previous
//
#include <hip/hip_runtime.h>
#include <hip/hip_bf16.h>
#include <math.h>

#define N_NODES 50000
#define N_EDGES 800000
#define DIM 128
#define CLS 32
#define NGRAPH 64
#define LN_EPS 1e-5f
// padded CSR capacity: sum ceil(deg/8)*8 <= E + 7*N
#define CSR_CAP (N_EDGES + 8 * N_NODES)
#define NBLK ((N_NODES + 255) / 256)   // 196 scan blocks

typedef __attribute__((ext_vector_type(8))) short bf16x8;
typedef __attribute__((ext_vector_type(4))) float f32x4;

static __device__ __forceinline__ int lower_bound_i(const int* a, int n, int key) {
    int lo = 0, hi = n;
    while (lo < hi) { int mid = (lo + hi) >> 1; if (a[mid] < key) lo = mid + 1; else hi = mid; }
    return lo;
}

// ---- one-shot zero of all small scratch (replaces 6 memsets) ---------------

__global__ __launch_bounds__(256) void zero_aux_kernel(
    int* __restrict__ counts, float* __restrict__ gsum,
    __hip_bfloat16* __restrict__ padA, __hip_bfloat16* __restrict__ padB,
    __hip_bfloat16* __restrict__ padC, __hip_bfloat16* __restrict__ padD) {
    int i = blockIdx.x * 256 + threadIdx.x;
    if (i < N_NODES) counts[i] = 0;
    if (i < NGRAPH * DIM) gsum[i] = 0.f;
    if (i < DIM) {
        padA[i] = __float2bfloat16(0.f);
        padB[i] = __float2bfloat16(0.f);
        padC[i] = __float2bfloat16(0.f);
        padD[i] = __float2bfloat16(0.f);
    }
}

// ---- CSR build (dst-bucketed, padded to multiple of 8 per node) ------------

__global__ void hist_kernel(const int* __restrict__ dst, int* __restrict__ cnt) {
    int e0 = (blockIdx.x * blockDim.x + threadIdx.x) * 4;
    if (e0 >= N_EDGES) return;  // N_EDGES % 4 == 0
    int4 d = *(const int4*)(dst + e0);
    atomicAdd(&cnt[d.x], 1);
    atomicAdd(&cnt[d.y], 1);
    atomicAdd(&cnt[d.z], 1);
    atomicAdd(&cnt[d.w], 1);
}

// hierarchical exclusive scan of padded counts, 3 stages, all parallel
__global__ __launch_bounds__(256) void scan_part1_kernel(const int* __restrict__ cnt,
                                                         int* __restrict__ bsum) {
    __shared__ int sd[256];
    int gi = blockIdx.x * 256 + threadIdx.x;
    int v = (gi < N_NODES) ? ((cnt[gi] + 7) & ~7) : 0;
    sd[threadIdx.x] = v;
    __syncthreads();
    for (int o = 128; o > 0; o >>= 1) {
        if (threadIdx.x < o) sd[threadIdx.x] += sd[threadIdx.x + o];
        __syncthreads();
    }
    if (threadIdx.x == 0) bsum[blockIdx.x] = sd[0];
}

__global__ __launch_bounds__(256) void scan_part2_kernel(int* __restrict__ bsum) {
    __shared__ int sd[256];
    int i = threadIdx.x;
    int v = (i < NBLK) ? bsum[i] : 0;
    sd[i] = v;
    __syncthreads();
    for (int o = 1; o < 256; o <<= 1) {
        int t = (i >= o) ? sd[i - o] : 0;
        __syncthreads();
        sd[i] += t;
        __syncthreads();
    }
    if (i < NBLK) bsum[i] = sd[i] - v;  // exclusive
}

// writes off[], cursor[]=off[] (fill_csr then needs no off[] load), and the
// pad slots of csr (<=7 per node) so init_csr is unnecessary.
__global__ __launch_bounds__(256) void scan_part3_kernel(const int* __restrict__ cnt,
                                                         const int* __restrict__ bsum,
                                                         int* __restrict__ off,
                                                         int* __restrict__ cursor,
                                                         int* __restrict__ csr) {
    __shared__ int sd[256];
    int gi = blockIdx.x * 256 + threadIdx.x;
    int i = threadIdx.x;
    int c = (gi < N_NODES) ? cnt[gi] : 0;
    int v = (c + 7) & ~7;  // padded
    sd[i] = v;
    __syncthreads();
    for (int o = 1; o < 256; o <<= 1) {
        int t = (i >= o) ? sd[i - o] : 0;
        __syncthreads();
        sd[i] += t;
        __syncthreads();
    }
    int incl = sd[i];
    int base = bsum[blockIdx.x];
    if (gi < N_NODES) {
        int offv = base + incl - v;
        off[gi] = offv;
        cursor[gi] = offv;
        for (int j = c; j < v; j++) csr[offv + j] = N_NODES;  // pad -> zero row
    }
    if (gi == N_NODES - 1) off[N_NODES] = base + incl;
}

__global__ void fill_csr_kernel(const int* __restrict__ src, const int* __restrict__ dst,
                                int* __restrict__ cursor, int* __restrict__ csr_src) {
    int e0 = (blockIdx.x * blockDim.x + threadIdx.x) * 4;
    if (e0 >= N_EDGES) return;  // N_EDGES % 4 == 0
    int4 d = *(const int4*)(dst + e0);
    int4 s = *(const int4*)(src + e0);
    int p0 = atomicAdd(&cursor[d.x], 1);
    int p1 = atomicAdd(&cursor[d.y], 1);
    int p2 = atomicAdd(&cursor[d.z], 1);
    int p3 = atomicAdd(&cursor[d.w], 1);
    csr_src[p0] = s.x;
    csr_src[p1] = s.y;
    csr_src[p2] = s.z;
    csr_src[p3] = s.w;
}

// ---- weight prep: WT[l][n][k] bf16, k<128 -> Wself[l][k][n], else Wmsg -----

__global__ void prep_w_kernel(const float* __restrict__ Wself,
                              const float* __restrict__ Wmsg,
                              __hip_bfloat16* __restrict__ WT) {
    int i = blockIdx.x * blockDim.x + threadIdx.x;
    if (i >= 3 * 128 * 256) return;
    int l = i / (128 * 256);
    int rem = i - l * (128 * 256);
    int n = rem >> 8;
    int k = rem & 255;
    float v = (k < 128) ? Wself[l * 16384 + k * 128 + n]
                        : Wmsg[l * 16384 + (k - 128) * 128 + n];
    WT[i] = __float2bfloat16(v);
}

// ---- fp32 -> bf16 shadow copy ----------------------------------------------

__global__ void f32_to_bf16_kernel(const float* __restrict__ in,
                                   __hip_bfloat16* __restrict__ out) {
    int i = blockIdx.x * blockDim.x + threadIdx.x;  // per 2 elements
    if (i < N_NODES * DIM / 2) {
        float2 v = ((const float2*)in)[i];
        ((__hip_bfloat162*)out)[i] = __float22bfloat162_rn(v);
    }
}

// ---- Neighbor sum: Sb[n,:] = sum_{e in CSR[n]} Xb[src[e],:] (bf16 in/out) --
// One wave per node; 16 independent gathers in flight (8-edge tail); fp32 acc.

__global__ __launch_bounds__(256) void agg_kernel(const __hip_bfloat16* __restrict__ Xb,
                                                  const int* __restrict__ off,
                                                  const int* __restrict__ csr,
                                                  __hip_bfloat16* __restrict__ Sb) {
    int wave = threadIdx.x >> 6;
    int lane = threadIdx.x & 63;
    int n = blockIdx.x * 4 + wave;
    if (n >= N_NODES) return;
    int b = off[n], e = off[n + 1];  // padded: (e-b) % 8 == 0
    float ax = 0.f, ay = 0.f;
    const size_t coloff = (size_t)(lane * 2);
    int base = b;
    for (; base + 16 <= e; base += 16) {
        int idx16 = csr[base + (lane & 15)];
        int s[16];
        unsigned int v[16];
#pragma unroll
        for (int j = 0; j < 16; j++) s[j] = __shfl(idx16, j, 64);
#pragma unroll
        for (int j = 0; j < 16; j++)
            v[j] = *(const unsigned int*)(Xb + (size_t)s[j] * DIM + coloff);
#pragma unroll
        for (int j = 0; j < 16; j++) {
            union { unsigned int u; float f; } lo, hi;
            lo.u = v[j] << 16;
            hi.u = v[j] & 0xffff0000u;
            ax += lo.f;
            ay += hi.f;
        }
    }
    if (base < e) {  // 8-edge tail
        int idx8 = csr[base + (lane & 7)];
        int s[8];
        unsigned int v[8];
#pragma unroll
        for (int j = 0; j < 8; j++) s[j] = __shfl(idx8, j, 64);
#pragma unroll
        for (int j = 0; j < 8; j++)
            v[j] = *(const unsigned int*)(Xb + (size_t)s[j] * DIM + coloff);
#pragma unroll
        for (int j = 0; j < 8; j++) {
            union { unsigned int u; float f; } lo, hi;
            lo.u = v[j] << 16;
            hi.u = v[j] & 0xffff0000u;
            ax += lo.f;
            ay += hi.f;
        }
    }
    ((__hip_bfloat162*)(Sb + (size_t)n * DIM))[lane] =
        __float22bfloat162_rn(make_float2(ax, ay));
}

// ---- Fused layer via MFMA: H = [Xb|Sb] @ WT^T; +bias+deg*bmsg, ReLU, LN ----

__global__ __launch_bounds__(256) void layer_mfma_kernel(
    const __hip_bfloat16* __restrict__ Xb, const __hip_bfloat16* __restrict__ Sb,
    const __hip_bfloat16* __restrict__ WT,  // [128 n][256 k] bf16 for this layer
    const float* __restrict__ bself, const float* __restrict__ bmsg,
    const int* __restrict__ deg,
    const float* __restrict__ lng, const float* __restrict__ lnb,
    __hip_bfloat16* __restrict__ XoutB, int do_ln) {
    // stride 136 bf16 = 272 B (16B-aligned rows, 2-way bank aliasing = free)
    __shared__ __hip_bfloat16 wlds[128 * 136];
    const int tid = threadIdx.x;
    const int w = tid >> 6, lane = tid & 63;
    const int l15 = lane & 15, q = lane >> 4;

    const int row = blockIdx.x * 64 + w * 16 + l15;
    const int rowc = min(row, N_NODES);  // pad row N_NODES is all zeros

    f32x4 acc[8];
#pragma unroll
    for (int ct = 0; ct < 8; ct++) acc[ct] = (f32x4){0.f, 0.f, 0.f, 0.f};

    const __hip_bfloat16* Abase[2] = {Xb, Sb};
    for (int c = 0; c < 2; c++) {
        __syncthreads();  // protect previous chunk's LDS reads
        {
            // stage WT[n][c*128 .. c*128+127] -> wlds[n][0..127]
            // 256 threads x 8 uint4 (128 B) = 32 KB = 128 rows x 128 bf16
            int n = tid >> 1, h = tid & 1;
            const uint4* src = (const uint4*)(WT + n * 256 + c * 128 + h * 64);
            uint4* dst = (uint4*)(&wlds[n * 136 + h * 64]);
#pragma unroll
            for (int i = 0; i < 8; i++) dst[i] = src[i];
        }
        __syncthreads();
        const __hip_bfloat16* arow = Abase[c] + (size_t)rowc * DIM;
#pragma unroll
        for (int ks = 0; ks < 4; ks++) {
            bf16x8 afrag = *(const bf16x8*)(arow + ks * 32 + q * 8);
#pragma unroll
            for (int ct = 0; ct < 8; ct++) {
                bf16x8 bfrag = *(const bf16x8*)(&wlds[(ct * 16 + l15) * 136 + ks * 32 + q * 8]);
                acc[ct] = __builtin_amdgcn_mfma_f32_16x16x32_bf16(afrag, bfrag, acc[ct], 0, 0, 0);
            }
        }
    }

    // epilogue: lane holds rows (q*4+r), cols (ct*16+l15)
    const int growbase = blockIdx.x * 64 + w * 16;
#pragma unroll
    for (int r = 0; r < 4; r++) {
        int grow = growbase + q * 4 + r;
        bool valid = grow < N_NODES;
        float dg = valid ? (float)deg[grow] : 0.f;
        float v[8];
        float s1 = 0.f;
#pragma unroll
        for (int ct = 0; ct < 8; ct++) {
            int col = ct * 16 + l15;
            float h = acc[ct][r] + bself[col] + dg * bmsg[col];
            h = fmaxf(h, 0.f);
            v[ct] = h;
            s1 += h;
        }
        if (do_ln) {
#pragma unroll
            for (int m = 1; m < 16; m <<= 1) s1 += __shfl_xor(s1, m, 64);
            float mu = s1 * (1.0f / 128.0f);
            float s2 = 0.f;
#pragma unroll
            for (int ct = 0; ct < 8; ct++) { float d = v[ct] - mu; s2 += d * d; }
#pragma unroll
            for (int m = 1; m < 16; m <<= 1) s2 += __shfl_xor(s2, m, 64);
            float rs = rsqrtf(s2 * (1.0f / 128.0f) + LN_EPS);
#pragma unroll
            for (int ct = 0; ct < 8; ct++) {
                int col = ct * 16 + l15;
                v[ct] = lng[col] * (v[ct] - mu) * rs + lnb[col];
            }
        }
        if (valid) {
#pragma unroll
            for (int ct = 0; ct < 8; ct++) {
                int col = ct * 16 + l15;
                XoutB[(size_t)grow * DIM + col] = __float2bfloat16(v[ct]);
            }
        }
    }
}

// ---- Global mean pool (partial sums) + head --------------------------------

__global__ __launch_bounds__(128) void pool_partial_kernel(const __hip_bfloat16* __restrict__ X,
                                                           const int* __restrict__ batch,
                                                           float* __restrict__ gsum) {
    int g = blockIdx.x;
    int s = blockIdx.y;
    int lo = lower_bound_i(batch, N_NODES, g);
    int hi = lower_bound_i(batch, N_NODES, g + 1);
    int len = hi - lo;
    int a = lo + (int)(((long long)len * s) / 8);
    int b = lo + (int)(((long long)len * (s + 1)) / 8);
    int c = threadIdx.x;
    float acc = 0.f;
    for (int n = a; n < b; n++) acc += __bfloat162float(X[(size_t)n * DIM + c]);
    if (b > a) atomicAdd(&gsum[g * DIM + c], acc);
}

__global__ __launch_bounds__(128) void head_kernel(
    const float* __restrict__ gsum, const int* __restrict__ batch,
    const float* __restrict__ W1, const float* __restrict__ b1,
    const float* __restrict__ W2, const float* __restrict__ b2,
    float* __restrict__ out) {
    __shared__ float p[128];
    __shared__ float hh[128];
    int g = blockIdx.x;
    int j = threadIdx.x;
    int lo = lower_bound_i(batch, N_NODES, g);
    int hi = lower_bound_i(batch, N_NODES, g + 1);
    float cnt = fmaxf((float)(hi - lo), 1.0f);
    p[j] = gsum[g * DIM + j] / cnt;
    __syncthreads();
    float s = b1[j];
    for (int k = 0; k < DIM; k++) s += p[k] * W1[k * DIM + j];
    hh[j] = s;
    __syncthreads();
    if (j < CLS) {
        float l = b2[j];
        for (int k = 0; k < DIM; k++) l += hh[k] * W2[k * CLS + j];
        float mx = l;
#pragma unroll
        for (int m = 16; m >= 1; m >>= 1) mx = fmaxf(mx, __shfl_xor(mx, m, 64));
        float ex = expf(l - mx);
        float se = ex;
#pragma unroll
        for (int m = 16; m >= 1; m >>= 1) se += __shfl_xor(se, m, 64);
        out[g * CLS + j] = l - mx - logf(se);
    }
}

// ---- launch ----------------------------------------------------------------

extern "C" void kernel_launch(void* const* d_in, const int* in_sizes, int n_in,
                              void* d_out, int out_size, void* d_ws, size_t ws_size,
                              hipStream_t stream) {
    (void)in_sizes; (void)n_in; (void)out_size; (void)ws_size;
    const float* x     = (const float*)d_in[0];
    const float* Wself = (const float*)d_in[1];
    const float* bself = (const float*)d_in[2];
    const float* Wmsg  = (const float*)d_in[3];
    const float* bmsg  = (const float*)d_in[4];
    const float* lng   = (const float*)d_in[5];
    const float* lnb   = (const float*)d_in[6];
    const float* W1    = (const float*)d_in[7];
    const float* b1    = (const float*)d_in[8];
    const float* W2    = (const float*)d_in[9];
    const float* b2    = (const float*)d_in[10];
    const int*   ei    = (const int*)d_in[11];
    const int*   batch = (const int*)d_in[12];
    const int* esrc = ei;
    const int* edst = ei + N_EDGES;

    char* w = (char*)d_ws;
    size_t o = 0;
    auto alloc = [&](size_t bytes) { void* p = w + o; o += (bytes + 255) & ~(size_t)255; return p; };
    __hip_bfloat16* XbIn = (__hip_bfloat16*)alloc((size_t)(N_NODES + 1) * DIM * 2);
    __hip_bfloat16* Xb0  = (__hip_bfloat16*)alloc((size_t)(N_NODES + 1) * DIM * 2);
    __hip_bfloat16* Xb1  = (__hip_bfloat16*)alloc((size_t)(N_NODES + 1) * DIM * 2);
    __hip_bfloat16* Sb   = (__hip_bfloat16*)alloc((size_t)(N_NODES + 1) * DIM * 2);
    __hip_bfloat16* WT   = (__hip_bfloat16*)alloc((size_t)3 * 128 * 256 * 2);
    int*   counts = (int*)alloc((size_t)N_NODES * 4);
    int*   cursor = (int*)alloc((size_t)N_NODES * 4);
    int*   offs   = (int*)alloc((size_t)(N_NODES + 1) * 4);
    int*   bsum   = (int*)alloc((size_t)NBLK * 4);
    int*   csr    = (int*)alloc((size_t)CSR_CAP * 4);
    float* gsum   = (float*)alloc((size_t)NGRAPH * DIM * 4);

    // zero counts/gsum/pad-rows in one dispatch (replaces all memsets)
    zero_aux_kernel<<<(N_NODES + 255) / 256, 256, 0, stream>>>(
        counts, gsum,
        XbIn + (size_t)N_NODES * DIM, Xb0 + (size_t)N_NODES * DIM,
        Xb1 + (size_t)N_NODES * DIM, Sb + (size_t)N_NODES * DIM);

    // CSR build (padded to 8 per node; pad slots -> zero row N_NODES)
    hist_kernel<<<(N_EDGES / 4 + 255) / 256, 256, 0, stream>>>(edst, counts);
    scan_part1_kernel<<<NBLK, 256, 0, stream>>>(counts, bsum);
    scan_part2_kernel<<<1, 256, 0, stream>>>(bsum);
    scan_part3_kernel<<<NBLK, 256, 0, stream>>>(counts, bsum, offs, cursor, csr);
    fill_csr_kernel<<<(N_EDGES / 4 + 255) / 256, 256, 0, stream>>>(esrc, edst, cursor, csr);

    // weights -> bf16 transposed; input -> bf16
    prep_w_kernel<<<(3 * 128 * 256 + 255) / 256, 256, 0, stream>>>(Wself, Wmsg, WT);
    f32_to_bf16_kernel<<<(N_NODES * DIM / 2 + 255) / 256, 256, 0, stream>>>(x, XbIn);

    const __hip_bfloat16* XbCur = XbIn;
    __hip_bfloat16* bbufs[3] = {Xb0, Xb1, Xb0};
    for (int i = 0; i < 3; i++) {
        agg_kernel<<<(N_NODES + 3) / 4, 256, 0, stream>>>(XbCur, offs, csr, Sb);
        layer_mfma_kernel<<<(N_NODES + 63) / 64, 256, 0, stream>>>(
            XbCur, Sb, WT + (size_t)i * 128 * 256,
            bself + i * DIM, bmsg + i * DIM, counts,
            (i < 2) ? lng + i * DIM : lng, (i < 2) ? lnb + i * DIM : lnb,
            bbufs[i], (i < 2) ? 1 : 0);
        XbCur = bbufs[i];
    }

    pool_partial_kernel<<<dim3(NGRAPH, 8), 128, 0, stream>>>(bbufs[2], batch, gsum);
    head_kernel<<<NGRAPH, 128, 0, stream>>>(gsum, batch, W1, b1, W2, b2, (float*)d_out);
}